// Round 10
// baseline (162.560 us; speedup 1.0000x reference)
//
#include <hip/hip_runtime.h>
#include <math.h>

#define INV_SQRT2 0.70710678118654752f
#define INV_SQRT32 0.17677669529663689f

// 4 threads per element (quad q = t&3). 256 thr/block -> 64 elements/block.
// Each lane KEEPS its 2 normalized x-rows in registers (xm/sc/xc read regs,
// not LDS) -> kills the 4-way bank conflicts of round 9 (9.0M conflicts).
// LDS x copy is read ONLY by quad-uniform (broadcast) MHA row streams.
// Work split with UNIFORM control flow: 1 MHA head/lane, 8 MLP neurons/lane,
// 2 x-rows/lane, argmin quartered. Order-sensitive sums (xm, mhs, o8, xc) use
// canonical butterfly ((p0+p1)+(p2+p3)) so all 4 lanes hold identical bits.
// No occupancy attributes (rounds 2-6: every hint => allocator over-squeeze
// => catastrophic scratch spill).
__device__ __forceinline__ void nearest_d8(const float* xx, float* y) {
  float f[8], err[8];
#pragma unroll
  for (int d = 0; d < 8; ++d) { f[d] = rintf(xx[d]); err[d] = xx[d] - f[d]; }
  int idx = 0; float best = -1.0f;
#pragma unroll
  for (int d = 0; d < 8; ++d) { float a = fabsf(err[d]); if (a > best) { best = a; idx = d; } }
  float fs = 0.f;
#pragma unroll
  for (int d = 0; d < 8; ++d) fs += f[d];
  bool ok = ((((int)fs) & 1) == 0);
#pragma unroll
  for (int d = 0; d < 8; ++d) {
    float g = f[d] + ((d == idx) ? ((err[d] >= 0.f) ? 1.f : -1.f) : 0.f);
    y[d] = ok ? f[d] : g;
  }
}

// canonical quad sum ((p0+p1)+(p2+p3)); all 4 lanes end with identical bits
__device__ __forceinline__ float qsum(float v, int q) {
  float o1 = __shfl_xor(v, 1, 64);
  float s1 = (q & 1) ? (o1 + v) : (v + o1);
  float o2 = __shfl_xor(s1, 2, 64);
  return (q & 2) ? (o2 + s1) : (s1 + o2);
}

extern "C" __global__ void __launch_bounds__(256)
e8_kernel(const float* __restrict__ colony, const float* __restrict__ conf,
          const float* __restrict__ Wq, const float* __restrict__ bq,
          const float* __restrict__ Wk, const float* __restrict__ bk,
          const float* __restrict__ Wv, const float* __restrict__ bv,
          const float* __restrict__ comm, const float* __restrict__ role,
          const float* __restrict__ mha_w, const float* __restrict__ mha_b,
          const float* __restrict__ W1, const float* __restrict__ b1,
          const float* __restrict__ W2, const float* __restrict__ b2,
          const float* __restrict__ gate, float* __restrict__ out, int B)
{
  __shared__ float x_lds[56 * 65];    // [feature f][elem eloc], stride 65
  __shared__ float wlds[7 * 64];      // block's outw image for coalesced store
  __shared__ float sM8[64], sU[8], sV[8], sCc[1];
  __shared__ float sComm[49], sRole[7];
  __shared__ float sWq3[64], sWk3[64], sBq3[8], sBk3[8];
  __shared__ float sWv[64], sBv[8];
  __shared__ float sW1[256], sB1[32], sW2[256], sB2[8];
  __shared__ float sGate[1];

  const int t = threadIdx.x;
  if (t < 64) {
    int i = t >> 3, j = t & 7;
    float a = 0.f;
    for (int h = 0; h < 32; ++h) a += Wq[h * 8 + i] * Wk[h * 8 + j];
    sM8[t] = a;
    sWq3[t] = mha_w[t];
    sWk3[t] = mha_w[64 + t];
    sWv[t] = Wv[t];
  } else if (t < 72) {
    int j = t - 64;
    float a = 0.f, bb = 0.f;
    for (int h = 0; h < 32; ++h) { a += bq[h] * Wk[h * 8 + j]; bb += bk[h] * Wq[h * 8 + j]; }
    sU[j] = a; sV[j] = bb;
    sBq3[j] = mha_b[j]; sBk3[j] = mha_b[8 + j]; sBv[j] = bv[j]; sB2[j] = b2[j];
  } else if (t == 72) {
    float c = 0.f;
    for (int h = 0; h < 32; ++h) c += bq[h] * bk[h];
    sCc[0] = c;
    sGate[0] = 1.f / (1.f + expf(-gate[0]));
  } else if (t >= 80 && t < 87) {
    int n = t - 80;
    float mx = -1e30f;
    for (int m = 0; m < 7; ++m) mx = fmaxf(mx, comm[n * 7 + m]);
    float ee[7], s = 0.f;
    for (int m = 0; m < 7; ++m) { ee[m] = expf(comm[n * 7 + m] - mx); s += ee[m]; }
    for (int m = 0; m < 7; ++m) sComm[n * 7 + m] = ee[m] / s;
  } else if (t == 87) {
    float mx = -1e30f;
    for (int m = 0; m < 7; ++m) mx = fmaxf(mx, role[m]);
    float ee[7], s = 0.f;
    for (int m = 0; m < 7; ++m) { ee[m] = expf(role[m] - mx); s += ee[m]; }
    for (int m = 0; m < 7; ++m) sRole[m] = ee[m] / s;
  }
  sW1[t] = W1[t];
  sW2[t] = W2[t];
  if (t < 32) sB1[t] = b1[t];

  const int q    = t & 3;
  const int eloc = t >> 2;
  const int el   = blockIdx.x * 64 + eloc;
  const int ec   = (el < B) ? el : (B - 1);   // clamped loads, no early return
  const bool q3  = (q < 3);
  const int n1 = q;
  const int n2 = q3 ? q + 4 : 3;   // lane3 harmlessly redoes row 3

#define LDX(n, j) x_lds[(((n) << 3) + (j)) * 65 + eloc]

  // ---- load + normalize my 2 rows -> registers AND LDS ----
  float rowA[8], rowB[8];
  {
    const float* px = colony + (size_t)ec * 56;
#pragma unroll
    for (int rr = 0; rr < 2; ++rr) {
      int n = rr ? n2 : n1;
      float4 v0 = *(const float4*)(px + n * 8);
      float4 v1 = *(const float4*)(px + n * 8 + 4);
      float row[8] = { v0.x, v0.y, v0.z, v0.w, v1.x, v1.y, v1.z, v1.w };
      float ss = 0.f;
#pragma unroll
      for (int d = 0; d < 8; ++d) ss += row[d] * row[d];
      float inv = 1.0f / fmaxf(sqrtf(ss), 1e-12f);
#pragma unroll
      for (int d = 0; d < 8; ++d) {
        float v = row[d] * inv;
        x_lds[((n << 3) + d) * 65 + eloc] = v;
        if (rr) rowB[d] = v; else rowA[d] = v;
      }
    }
  }
  __syncthreads();

  // ---- xm via canonical quad sum (register rows) ----
  float xm[8];
#pragma unroll
  for (int d = 0; d < 8; ++d) {
    float p = q3 ? (rowA[d] + rowB[d]) : rowA[d];
    xm[d] = qsum(p, q) * (1.0f / 7.0f);
  }

  // ---- w8 split: lane q owns j=q and j=q+4 (exact sequential dots) ----
  float w8[8];
  {
    float a0 = 0.f, a1 = 0.f;
#pragma unroll
    for (int i = 0; i < 8; ++i) {
      a0 += xm[i] * sM8[i * 8 + q];
      a1 += xm[i] * sM8[i * 8 + q + 4];
    }
    a0 += sU[q]; a1 += sU[q + 4];
#pragma unroll
    for (int j = 0; j < 4; ++j) w8[j] = __shfl(a0, j, 4);
#pragma unroll
    for (int j = 4; j < 8; ++j) w8[j] = __shfl(a1, j - 4, 4);
  }
  float base = sCc[0];
#pragma unroll
  for (int i = 0; i < 8; ++i) base += sV[i] * xm[i];

  // ---- sc split: lane q owns n1, n2 (register rows) ----
  float sc[7];
  {
    float sA = base, sB_ = base;
#pragma unroll
    for (int j = 0; j < 8; ++j) {
      sA  += w8[j] * rowA[j];
      sB_ += w8[j] * rowB[j];
    }
    sA *= INV_SQRT32; sB_ *= INV_SQRT32;
#pragma unroll
    for (int n = 0; n < 4; ++n) sc[n] = __shfl(sA, n, 4);
#pragma unroll
    for (int n = 4; n < 7; ++n) sc[n] = __shfl(sB_, n - 4, 4);
  }

  // ---- sc2 split: lane q owns m=q and m=n2 ----
  float sc2[7];
  {
    float a0 = 0.f, a1 = 0.f;
#pragma unroll
    for (int n = 0; n < 7; ++n) {
      a0 += sc[n] * sComm[n * 7 + q];
      a1 += sc[n] * sComm[n * 7 + n2];
    }
    a0 += sRole[q]; a1 += sRole[n2];
#pragma unroll
    for (int m = 0; m < 4; ++m) sc2[m] = __shfl(a0, m, 4);
#pragma unroll
    for (int m = 4; m < 7; ++m) sc2[m] = __shfl(a1, m - 4, 4);
  }

  // ---- MHA: 1 head per lane (h = q); rows streamed via LDS broadcast ----
  float mhs[7];
  {
    float Kh[7][2], Qh[7][2];
#pragma unroll
    for (int m = 0; m < 7; ++m) {
      float row[8];
#pragma unroll
      for (int j = 0; j < 8; ++j) row[j] = LDX(m, j);
      float k0 = sBk3[2 * q], k1 = sBk3[2 * q + 1];
      float q0 = sBq3[2 * q], q1 = sBq3[2 * q + 1];
#pragma unroll
      for (int j = 0; j < 8; ++j) {
        k0 += row[j] * sWk3[(2 * q) * 8 + j];
        k1 += row[j] * sWk3[(2 * q + 1) * 8 + j];
        q0 += row[j] * sWq3[(2 * q) * 8 + j];
        q1 += row[j] * sWq3[(2 * q + 1) * 8 + j];
      }
      Kh[m][0] = k0; Kh[m][1] = k1;
      Qh[m][0] = q0; Qh[m][1] = q1;
    }
    float mp[7];
#pragma unroll
    for (int m = 0; m < 7; ++m) mp[m] = 0.f;
#pragma unroll
    for (int n = 0; n < 7; ++n) {
      float ex[7], mx = -1e30f;
#pragma unroll
      for (int m = 0; m < 7; ++m) {
        float a = Qh[n][0] * Kh[m][0] + Qh[n][1] * Kh[m][1];
        ex[m] = a * INV_SQRT2;
        mx = fmaxf(mx, ex[m]);
      }
      float s = 0.f;
#pragma unroll
      for (int m = 0; m < 7; ++m) { ex[m] = __expf(ex[m] - mx); s += ex[m]; }
      float inv = 1.0f / s;
#pragma unroll
      for (int m = 0; m < 7; ++m) mp[m] += ex[m] * inv;
    }
#pragma unroll
    for (int m = 0; m < 7; ++m) mhs[m] = qsum(mp[m], q);
  }

  // ---- combine scores, softmax, confidence re-norm (redundant, identical) ----
  float scf[7], mx2 = -1e30f;
#pragma unroll
  for (int m = 0; m < 7; ++m) {
    scf[m] = 0.7f * sc2[m] + 0.3f * ((mhs[m] * 0.25f) * (1.0f / 7.0f));
    mx2 = fmaxf(mx2, scf[m]);
  }
  float ew[7], s2 = 0.f;
#pragma unroll
  for (int m = 0; m < 7; ++m) { ew[m] = __expf(scf[m] - mx2); s2 += ew[m]; }
  float sinv = 1.0f / s2;
  float w[7], ws = 0.f;
  const float* pc = conf + (size_t)ec * 7;
#pragma unroll
  for (int m = 0; m < 7; ++m) { w[m] = (ew[m] * sinv) * pc[m]; ws += w[m]; }
  float dinv = 1.0f / fmaxf(ws, 1e-8f);
#pragma unroll
  for (int m = 0; m < 7; ++m) w[m] = w[m] * dinv;

  if (q == 0) {
#pragma unroll
    for (int m = 0; m < 7; ++m) wlds[eloc * 7 + m] = w[m];
  }

  // ---- xc from register rows: per-lane partial + canonical quad sum ----
  float xc[8];
#pragma unroll
  for (int d = 0; d < 8; ++d) {
    float p = w[n1] * rowA[d];
    if (q3) p += w[n2] * rowB[d];
    xc[d] = qsum(p, q);
  }

  // ---- comb split: lane q owns i=q and i=q+4 ----
  float comb[8];
  {
    float a0 = sBv[q], a1 = sBv[q + 4];
#pragma unroll
    for (int j = 0; j < 8; ++j) {
      a0 += sWv[q * 8 + j] * xc[j];
      a1 += sWv[(q + 4) * 8 + j] * xc[j];
    }
#pragma unroll
    for (int i = 0; i < 4; ++i) comb[i] = __shfl(a0, i, 4);
#pragma unroll
    for (int i = 4; i < 8; ++i) comb[i] = __shfl(a1, i - 4, 4);
  }

  // ---- MLP: 8 neurons per lane (i = 8q..8q+7), canonical combine ----
  float o8[8];
  {
    float op[8];
#pragma unroll
    for (int k = 0; k < 8; ++k) op[k] = (q == 0) ? sB2[k] : 0.f;
#pragma unroll
    for (int ii = 0; ii < 8; ++ii) {
      int i = 8 * q + ii;
      float a = sB1[i];
#pragma unroll
      for (int j = 0; j < 8; ++j) a += sW1[i * 8 + j] * comb[j];
      float g = 0.5f * a * (1.f + erff(a * INV_SQRT2));
#pragma unroll
      for (int k = 0; k < 8; ++k) op[k] += sW2[k * 32 + i] * g;
    }
#pragma unroll
    for (int k = 0; k < 8; ++k) o8[k] = qsum(op[k], q);
  }

  // ---- refined = norm(combined + sigmoid(gate)*h) (redundant, identical) ----
  float gsig = sGate[0];
  float pre[8], ssq = 0.f;
#pragma unroll
  for (int d = 0; d < 8; ++d) { pre[d] = comb[d] + gsig * o8[d]; ssq += pre[d] * pre[d]; }
  float ninv = 1.0f / fmaxf(sqrtf(ssq), 1e-12f);
  float r[8];
#pragma unroll
  for (int d = 0; d < 8; ++d) r[d] = pre[d] * ninv;

  float* outq = out;
  float* outi = out + (size_t)B * 8;
  float* outw = out + (size_t)B * 9;

  // ---- nearest E8: lanes q<2 compute y0, q>=2 compute y1 ----
  {
    const int h2 = q >> 1;
    float xs[8], y[8];
#pragma unroll
    for (int d = 0; d < 8; ++d) xs[d] = h2 ? (r[d] - 0.5f) : r[d];
    nearest_d8(xs, y);
#pragma unroll
    for (int d = 0; d < 8; ++d) y[d] = h2 ? (y[d] + 0.5f) : y[d];
    float dow = 0.f;
#pragma unroll
    for (int d = 0; d < 8; ++d) { float dd = r[d] - y[d]; dow += dd * dd; }
    float doth = __shfl_xor(dow, 2, 64);
    float dd0 = h2 ? doth : dow;
    float dd1 = h2 ? dow : doth;
    bool use0 = (dd0 <= dd1);
    bool mine_wins = (use0 == (h2 == 0));
    if (mine_wins && ((q & 1) == 0) && el < B) {
      float qv[8];
#pragma unroll
      for (int d = 0; d < 8; ++d) qv[d] = r[d] + (y[d] - r[d]);
      *(float4*)(outq + (size_t)el * 8)     = make_float4(qv[0], qv[1], qv[2], qv[3]);
      *(float4*)(outq + (size_t)el * 8 + 4) = make_float4(qv[4], qv[5], qv[6], qv[7]);
    }
  }

  // ---- argmin over 240 E8 roots, quartered ----
  float ssum = 0.f;
#pragma unroll
  for (int d = 0; d < 8; ++d) ssum += r[d] * r[d];
  float bestSq = 1e30f;
  int bestIdx = 0;
  // integer roots: lane q takes sign-combo s4=q of every (i,j) pair
  {
    int idx = 0;
#pragma unroll
    for (int i = 0; i < 8; ++i) {
#pragma unroll
      for (int j = i + 1; j < 8; ++j) {
        float a = r[i] + r[j];       // s4: 0=a, 1=b, 2=-b, 3=-a
        float bb = r[i] - r[j];
        float t1 = (q & 2) ? -bb : a;
        float t2 = (q & 2) ? -a  : bb;
        float c  = (q & 1) ? t2 : t1;
        float sq = fmaf(-2.f, c, ssum) + 2.f;
        if (sq < bestSq) { bestSq = sq; bestIdx = idx; }
        idx += 4;
      }
    }
    bestIdx += q;   // absolute index (a hit always occurred)
  }
  // half-integer roots: lane q takes k = 32q..32q+31. Per-lane tables hold the
  // lane's slice of Thi/Tlo with build order preserved add-by-add, so every T
  // matches the (passing) full-table chain bit-for-bit.
  {
    float hr[8];
#pragma unroll
    for (int d = 0; d < 8; ++d) hr[d] = 0.5f * r[d];
    float sumhr = ((hr[0] + hr[1]) + (hr[2] + hr[3])) + ((hr[4] + hr[5]) + (hr[6] + hr[7]));
    float tb0 = (q & 2) ? hr[0] : 0.f;
    float tb  = (q & 1) ? (tb0 + hr[1]) : tb0;
    float Th[4];
    Th[0] = tb;
    Th[1] = tb + hr[3];
    Th[2] = tb + hr[2];
    Th[3] = (tb + hr[2]) + hr[3];
    float TloB[8];
    TloB[0] = 0.f;
    TloB[4] = 0.f + hr[4];
    TloB[2] = 0.f + hr[5];
    TloB[6] = hr[4] + hr[5];
    TloB[1] = 0.f + hr[6];
    TloB[5] = hr[4] + hr[6];
    TloB[3] = hr[5] + hr[6];
    TloB[7] = (hr[4] + hr[5]) + hr[6];
    const int pq = ((q >> 1) ^ q) & 1;          // popc(q)&1
    const float hpE = pq ? hr[7] : 0.f;         // parity(kk)==0 -> add iff pq
    const float hpO = pq ? 0.f : hr[7];         // parity(kk)==1 -> add iff !pq
    const int hbase = 112 + (q << 5);
#pragma unroll
    for (int kk = 0; kk < 32; ++kk) {
      float tl = TloB[kk & 7] + ((__popc(kk) & 1) ? hpO : hpE);
      float T = Th[kk >> 3] + tl;
      float dot = sumhr - 2.f * T;
      float sq = fmaf(-2.f, dot, ssum) + 2.f;
      if (sq < bestSq) { bestSq = sq; bestIdx = hbase + kk; }
    }
  }
  // cross-lane combine: lexicographic (sq, idx) min == global first-min
  {
#pragma unroll
    for (int mlev = 1; mlev <= 2; mlev <<= 1) {
      float oSq = __shfl_xor(bestSq, mlev, 64);
      int   oIx = __shfl_xor(bestIdx, mlev, 64);
      if (oSq < bestSq || (oSq == bestSq && oIx < bestIdx)) { bestSq = oSq; bestIdx = oIx; }
    }
    if (q == 0 && el < B) outi[el] = (float)bestIdx;
  }

  // ---- coalesced weights store ----
  __syncthreads();
  {
    const size_t wbase = (size_t)blockIdx.x * 448;
    const size_t wtot = (size_t)B * 7;
#pragma unroll
    for (int k2 = 0; k2 < 2; ++k2) {
      int idx2 = k2 * 256 + t;
      if (idx2 < 448 && wbase + idx2 < wtot) outw[wbase + idx2] = wlds[idx2];
    }
  }
#undef LDX
}

extern "C" void kernel_launch(void* const* d_in, const int* in_sizes, int n_in,
                              void* d_out, int out_size, void* d_ws, size_t ws_size,
                              hipStream_t stream) {
  const float* colony = (const float*)d_in[0];
  const float* conf   = (const float*)d_in[1];
  const float* Wq     = (const float*)d_in[2];
  const float* bq     = (const float*)d_in[3];
  const float* Wk     = (const float*)d_in[4];
  const float* bk     = (const float*)d_in[5];
  const float* Wv     = (const float*)d_in[6];
  const float* bv     = (const float*)d_in[7];
  const float* comm   = (const float*)d_in[8];
  const float* role   = (const float*)d_in[9];
  const float* mhaw   = (const float*)d_in[10];
  const float* mhab   = (const float*)d_in[11];
  const float* W1     = (const float*)d_in[12];
  const float* b1     = (const float*)d_in[13];
  const float* W2     = (const float*)d_in[14];
  const float* b2     = (const float*)d_in[15];
  const float* gate   = (const float*)d_in[16];

  int B = in_sizes[0] / 56;
  dim3 grid((B + 63) / 64), block(256);
  hipLaunchKernelGGL(e8_kernel, grid, block, 0, stream,
                     colony, conf, Wq, bq, Wk, bk, Wv, bv, comm, role,
                     mhaw, mhab, W1, b1, W2, b2, gate, (float*)d_out, B);
}

// Round 11
// 146.182 us; speedup vs baseline: 1.1120x; 1.1120x over previous
//
#include <hip/hip_runtime.h>
#include <math.h>

#define INV_SQRT2 0.70710678118654752f
#define INV_SQRT32 0.17677669529663689f

// 4 threads per element (quad q = t&3). 256 thr/block -> 64 elements/block.
// Round-9 structure (148us) + conflict-free LDS layouts:
//  - x_lds is [elem][feature] stride 57: bank = (25e + f)%32 ->
//    xm/sc reads injective, xc <=2-way (free), MHA quad-broadcast clean.
//  - W1 stored TRANSPOSED (sW1T[j*32+i]) so MLP reads (i=8q+ii) hit
//    distinct banks (old layout: all 4 q-lanes same bank = 4-way on 64 reads).
// Work split with UNIFORM control flow: 1 MHA head/lane, 8 MLP neurons/lane,
// 2 x-rows/lane, argmin quartered. Order-sensitive sums (xm, mhs, o8) use
// canonical butterfly ((p0+p1)+(p2+p3)); all 4 lanes hold identical bits.
// No occupancy attributes (rounds 2-6: every hint => allocator over-squeeze
// => catastrophic scratch spill).
__device__ __forceinline__ void nearest_d8(const float* xx, float* y) {
  float f[8], err[8];
#pragma unroll
  for (int d = 0; d < 8; ++d) { f[d] = rintf(xx[d]); err[d] = xx[d] - f[d]; }
  int idx = 0; float best = -1.0f;
#pragma unroll
  for (int d = 0; d < 8; ++d) { float a = fabsf(err[d]); if (a > best) { best = a; idx = d; } }
  float fs = 0.f;
#pragma unroll
  for (int d = 0; d < 8; ++d) fs += f[d];
  bool ok = ((((int)fs) & 1) == 0);
#pragma unroll
  for (int d = 0; d < 8; ++d) {
    float g = f[d] + ((d == idx) ? ((err[d] >= 0.f) ? 1.f : -1.f) : 0.f);
    y[d] = ok ? f[d] : g;
  }
}

// canonical quad sum ((p0+p1)+(p2+p3)); all 4 lanes end with identical bits
__device__ __forceinline__ float qsum(float v, int q) {
  float o1 = __shfl_xor(v, 1, 64);
  float s1 = (q & 1) ? (o1 + v) : (v + o1);
  float o2 = __shfl_xor(s1, 2, 64);
  return (q & 2) ? (o2 + s1) : (s1 + o2);
}

extern "C" __global__ void __launch_bounds__(256)
e8_kernel(const float* __restrict__ colony, const float* __restrict__ conf,
          const float* __restrict__ Wq, const float* __restrict__ bq,
          const float* __restrict__ Wk, const float* __restrict__ bk,
          const float* __restrict__ Wv, const float* __restrict__ bv,
          const float* __restrict__ comm, const float* __restrict__ role,
          const float* __restrict__ mha_w, const float* __restrict__ mha_b,
          const float* __restrict__ W1, const float* __restrict__ b1,
          const float* __restrict__ W2, const float* __restrict__ b2,
          const float* __restrict__ gate, float* __restrict__ out, int B)
{
  __shared__ float x_lds[64 * 57];    // [elem eloc][feature f], stride 57
  __shared__ float wlds[7 * 64];      // block's outw image for coalesced store
  __shared__ float sM8[64], sU[8], sV[8], sCc[1];
  __shared__ float sComm[49], sRole[7];
  __shared__ float sWq3[64], sWk3[64], sBq3[8], sBk3[8];
  __shared__ float sWv[64], sBv[8];
  __shared__ float sW1T[256], sB1[32], sW2[256], sB2[8];
  __shared__ float sGate[1];

  const int t = threadIdx.x;
  if (t < 64) {
    int i = t >> 3, j = t & 7;
    float a = 0.f;
    for (int h = 0; h < 32; ++h) a += Wq[h * 8 + i] * Wk[h * 8 + j];
    sM8[t] = a;
    sWq3[t] = mha_w[t];
    sWk3[t] = mha_w[64 + t];
    sWv[t] = Wv[t];
  } else if (t < 72) {
    int j = t - 64;
    float a = 0.f, bb = 0.f;
    for (int h = 0; h < 32; ++h) { a += bq[h] * Wk[h * 8 + j]; bb += bk[h] * Wq[h * 8 + j]; }
    sU[j] = a; sV[j] = bb;
    sBq3[j] = mha_b[j]; sBk3[j] = mha_b[8 + j]; sBv[j] = bv[j]; sB2[j] = b2[j];
  } else if (t == 72) {
    float c = 0.f;
    for (int h = 0; h < 32; ++h) c += bq[h] * bk[h];
    sCc[0] = c;
    sGate[0] = 1.f / (1.f + expf(-gate[0]));
  } else if (t >= 80 && t < 87) {
    int n = t - 80;
    float mx = -1e30f;
    for (int m = 0; m < 7; ++m) mx = fmaxf(mx, comm[n * 7 + m]);
    float ee[7], s = 0.f;
    for (int m = 0; m < 7; ++m) { ee[m] = expf(comm[n * 7 + m] - mx); s += ee[m]; }
    for (int m = 0; m < 7; ++m) sComm[n * 7 + m] = ee[m] / s;
  } else if (t == 87) {
    float mx = -1e30f;
    for (int m = 0; m < 7; ++m) mx = fmaxf(mx, role[m]);
    float ee[7], s = 0.f;
    for (int m = 0; m < 7; ++m) { ee[m] = expf(role[m] - mx); s += ee[m]; }
    for (int m = 0; m < 7; ++m) sRole[m] = ee[m] / s;
  }
  sW1T[t] = W1[((t & 31) << 3) + (t >> 5)];   // sW1T[j*32+i] = W1[i*8+j]
  sW2[t] = W2[t];
  if (t < 32) sB1[t] = b1[t];

  const int q    = t & 3;
  const int eloc = t >> 2;
  const int el   = blockIdx.x * 64 + eloc;
  const int ec   = (el < B) ? el : (B - 1);   // clamped loads, no early return
  const bool q3  = (q < 3);
  const int n1 = q;
  const int n2 = q3 ? q + 4 : 3;   // lane3 harmlessly redoes row 3

#define LDX(n, j) x_lds[eloc * 57 + (((n) << 3) + (j))]

  // ---- load + normalize my 2 rows -> LDS ----
  {
    const float* px = colony + (size_t)ec * 56;
#pragma unroll
    for (int rr = 0; rr < 2; ++rr) {
      int n = rr ? n2 : n1;
      float4 v0 = *(const float4*)(px + n * 8);
      float4 v1 = *(const float4*)(px + n * 8 + 4);
      float row[8] = { v0.x, v0.y, v0.z, v0.w, v1.x, v1.y, v1.z, v1.w };
      float ss = 0.f;
#pragma unroll
      for (int d = 0; d < 8; ++d) ss += row[d] * row[d];
      float inv = 1.0f / fmaxf(sqrtf(ss), 1e-12f);
#pragma unroll
      for (int d = 0; d < 8; ++d) x_lds[eloc * 57 + ((n << 3) + d)] = row[d] * inv;
    }
  }
  __syncthreads();

  // ---- xm via canonical quad sum ----
  float xm[8];
#pragma unroll
  for (int d = 0; d < 8; ++d) {
    float a = LDX(n1, d);
    float bpart = LDX(n2, d);
    float p = q3 ? (a + bpart) : a;
    xm[d] = qsum(p, q) * (1.0f / 7.0f);
  }

  // ---- w8 split: lane q owns j=q and j=q+4 (exact sequential dots) ----
  float w8[8];
  {
    float a0 = 0.f, a1 = 0.f;
#pragma unroll
    for (int i = 0; i < 8; ++i) {
      a0 += xm[i] * sM8[i * 8 + q];
      a1 += xm[i] * sM8[i * 8 + q + 4];
    }
    a0 += sU[q]; a1 += sU[q + 4];
#pragma unroll
    for (int j = 0; j < 4; ++j) w8[j] = __shfl(a0, j, 4);
#pragma unroll
    for (int j = 4; j < 8; ++j) w8[j] = __shfl(a1, j - 4, 4);
  }
  float base = sCc[0];
#pragma unroll
  for (int i = 0; i < 8; ++i) base += sV[i] * xm[i];

  // ---- sc split: lane q owns n1, n2 ----
  float sc[7];
  {
    float sA = base, sB_ = base;
#pragma unroll
    for (int j = 0; j < 8; ++j) {
      sA  += w8[j] * LDX(n1, j);
      sB_ += w8[j] * LDX(n2, j);
    }
    sA *= INV_SQRT32; sB_ *= INV_SQRT32;
#pragma unroll
    for (int n = 0; n < 4; ++n) sc[n] = __shfl(sA, n, 4);
#pragma unroll
    for (int n = 4; n < 7; ++n) sc[n] = __shfl(sB_, n - 4, 4);
  }

  // ---- sc2 split: lane q owns m=q and m=n2 ----
  float sc2[7];
  {
    float a0 = 0.f, a1 = 0.f;
#pragma unroll
    for (int n = 0; n < 7; ++n) {
      a0 += sc[n] * sComm[n * 7 + q];
      a1 += sc[n] * sComm[n * 7 + n2];
    }
    a0 += sRole[q]; a1 += sRole[n2];
#pragma unroll
    for (int m = 0; m < 4; ++m) sc2[m] = __shfl(a0, m, 4);
#pragma unroll
    for (int m = 4; m < 7; ++m) sc2[m] = __shfl(a1, m - 4, 4);
  }

  // ---- MHA: 1 head per lane (h = q); rows via LDS quad-broadcast ----
  float mhs[7];
  {
    float Kh[7][2], Qh[7][2];
#pragma unroll
    for (int m = 0; m < 7; ++m) {
      float row[8];
#pragma unroll
      for (int j = 0; j < 8; ++j) row[j] = LDX(m, j);
      float k0 = sBk3[2 * q], k1 = sBk3[2 * q + 1];
      float q0 = sBq3[2 * q], q1 = sBq3[2 * q + 1];
#pragma unroll
      for (int j = 0; j < 8; ++j) {
        k0 += row[j] * sWk3[(2 * q) * 8 + j];
        k1 += row[j] * sWk3[(2 * q + 1) * 8 + j];
        q0 += row[j] * sWq3[(2 * q) * 8 + j];
        q1 += row[j] * sWq3[(2 * q + 1) * 8 + j];
      }
      Kh[m][0] = k0; Kh[m][1] = k1;
      Qh[m][0] = q0; Qh[m][1] = q1;
    }
    float mp[7];
#pragma unroll
    for (int m = 0; m < 7; ++m) mp[m] = 0.f;
#pragma unroll
    for (int n = 0; n < 7; ++n) {
      float ex[7], mx = -1e30f;
#pragma unroll
      for (int m = 0; m < 7; ++m) {
        float a = Qh[n][0] * Kh[m][0] + Qh[n][1] * Kh[m][1];
        ex[m] = a * INV_SQRT2;
        mx = fmaxf(mx, ex[m]);
      }
      float s = 0.f;
#pragma unroll
      for (int m = 0; m < 7; ++m) { ex[m] = __expf(ex[m] - mx); s += ex[m]; }
      float inv = 1.0f / s;
#pragma unroll
      for (int m = 0; m < 7; ++m) mp[m] += ex[m] * inv;
    }
#pragma unroll
    for (int m = 0; m < 7; ++m) mhs[m] = qsum(mp[m], q);
  }

  // ---- combine scores, softmax, confidence re-norm (redundant, identical) ----
  float scf[7], mx2 = -1e30f;
#pragma unroll
  for (int m = 0; m < 7; ++m) {
    scf[m] = 0.7f * sc2[m] + 0.3f * ((mhs[m] * 0.25f) * (1.0f / 7.0f));
    mx2 = fmaxf(mx2, scf[m]);
  }
  float ew[7], s2 = 0.f;
#pragma unroll
  for (int m = 0; m < 7; ++m) { ew[m] = __expf(scf[m] - mx2); s2 += ew[m]; }
  float sinv = 1.0f / s2;
  float w[7], ws = 0.f;
  const float* pc = conf + (size_t)ec * 7;
#pragma unroll
  for (int m = 0; m < 7; ++m) { w[m] = (ew[m] * sinv) * pc[m]; ws += w[m]; }
  float dinv = 1.0f / fmaxf(ws, 1e-8f);
#pragma unroll
  for (int m = 0; m < 7; ++m) w[m] = w[m] * dinv;

  if (q == 0) {
#pragma unroll
    for (int m = 0; m < 7; ++m) wlds[eloc * 7 + m] = w[m];
  }

  // ---- xc split by dim: lane q owns d=q and d=q+4 (exact n-order chains) ----
  float xc[8];
  {
    float a0 = 0.f, a1 = 0.f;
#pragma unroll
    for (int n = 0; n < 7; ++n) {
      a0 += w[n] * LDX(n, q);
      a1 += w[n] * LDX(n, q + 4);
    }
#pragma unroll
    for (int d = 0; d < 4; ++d) xc[d] = __shfl(a0, d, 4);
#pragma unroll
    for (int d = 4; d < 8; ++d) xc[d] = __shfl(a1, d - 4, 4);
  }

  // ---- comb split: lane q owns i=q and i=q+4 ----
  float comb[8];
  {
    float a0 = sBv[q], a1 = sBv[q + 4];
#pragma unroll
    for (int j = 0; j < 8; ++j) {
      a0 += sWv[q * 8 + j] * xc[j];
      a1 += sWv[(q + 4) * 8 + j] * xc[j];
    }
#pragma unroll
    for (int i = 0; i < 4; ++i) comb[i] = __shfl(a0, i, 4);
#pragma unroll
    for (int i = 4; i < 8; ++i) comb[i] = __shfl(a1, i - 4, 4);
  }

  // ---- MLP: 8 neurons per lane (i = 8q..8q+7), canonical combine ----
  float o8[8];
  {
    float op[8];
#pragma unroll
    for (int k = 0; k < 8; ++k) op[k] = (q == 0) ? sB2[k] : 0.f;
#pragma unroll
    for (int ii = 0; ii < 8; ++ii) {
      int i = 8 * q + ii;
      float a = sB1[i];
#pragma unroll
      for (int j = 0; j < 8; ++j) a += sW1T[j * 32 + i] * comb[j];
      float g = 0.5f * a * (1.f + erff(a * INV_SQRT2));
#pragma unroll
      for (int k = 0; k < 8; ++k) op[k] += sW2[k * 32 + i] * g;
    }
#pragma unroll
    for (int k = 0; k < 8; ++k) o8[k] = qsum(op[k], q);
  }

  // ---- refined = norm(combined + sigmoid(gate)*h) (redundant, identical) ----
  float gsig = sGate[0];
  float pre[8], ssq = 0.f;
#pragma unroll
  for (int d = 0; d < 8; ++d) { pre[d] = comb[d] + gsig * o8[d]; ssq += pre[d] * pre[d]; }
  float ninv = 1.0f / fmaxf(sqrtf(ssq), 1e-12f);
  float r[8];
#pragma unroll
  for (int d = 0; d < 8; ++d) r[d] = pre[d] * ninv;

  float* outq = out;
  float* outi = out + (size_t)B * 8;
  float* outw = out + (size_t)B * 9;

  // ---- nearest E8: lanes q<2 compute y0, q>=2 compute y1 ----
  {
    const int h2 = q >> 1;
    float xs[8], y[8];
#pragma unroll
    for (int d = 0; d < 8; ++d) xs[d] = h2 ? (r[d] - 0.5f) : r[d];
    nearest_d8(xs, y);
#pragma unroll
    for (int d = 0; d < 8; ++d) y[d] = h2 ? (y[d] + 0.5f) : y[d];
    float dow = 0.f;
#pragma unroll
    for (int d = 0; d < 8; ++d) { float dd = r[d] - y[d]; dow += dd * dd; }
    float doth = __shfl_xor(dow, 2, 64);
    float dd0 = h2 ? doth : dow;
    float dd1 = h2 ? dow : doth;
    bool use0 = (dd0 <= dd1);
    bool mine_wins = (use0 == (h2 == 0));
    if (mine_wins && ((q & 1) == 0) && el < B) {
      float qv[8];
#pragma unroll
      for (int d = 0; d < 8; ++d) qv[d] = r[d] + (y[d] - r[d]);
      *(float4*)(outq + (size_t)el * 8)     = make_float4(qv[0], qv[1], qv[2], qv[3]);
      *(float4*)(outq + (size_t)el * 8 + 4) = make_float4(qv[4], qv[5], qv[6], qv[7]);
    }
  }

  // ---- argmin over 240 E8 roots, quartered ----
  float ssum = 0.f;
#pragma unroll
  for (int d = 0; d < 8; ++d) ssum += r[d] * r[d];
  float bestSq = 1e30f;
  int bestIdx = 0;
  // integer roots: lane q takes sign-combo s4=q of every (i,j) pair
  {
    int idx = 0;
#pragma unroll
    for (int i = 0; i < 8; ++i) {
#pragma unroll
      for (int j = i + 1; j < 8; ++j) {
        float a = r[i] + r[j];       // s4: 0=a, 1=b, 2=-b, 3=-a
        float bb = r[i] - r[j];
        float t1 = (q & 2) ? -bb : a;
        float t2 = (q & 2) ? -a  : bb;
        float c  = (q & 1) ? t2 : t1;
        float sq = fmaf(-2.f, c, ssum) + 2.f;
        if (sq < bestSq) { bestSq = sq; bestIdx = idx; }
        idx += 4;
      }
    }
    bestIdx += q;   // absolute index (a hit always occurred)
  }
  // half-integer roots: lane q takes k = 32q..32q+31. Per-lane tables hold the
  // lane's slice of Thi/Tlo with build order preserved add-by-add, so every T
  // matches the (passing) full-table chain bit-for-bit.
  {
    float hr[8];
#pragma unroll
    for (int d = 0; d < 8; ++d) hr[d] = 0.5f * r[d];
    float sumhr = ((hr[0] + hr[1]) + (hr[2] + hr[3])) + ((hr[4] + hr[5]) + (hr[6] + hr[7]));
    float tb0 = (q & 2) ? hr[0] : 0.f;
    float tb  = (q & 1) ? (tb0 + hr[1]) : tb0;
    float Th[4];
    Th[0] = tb;
    Th[1] = tb + hr[3];
    Th[2] = tb + hr[2];
    Th[3] = (tb + hr[2]) + hr[3];
    float TloB[8];
    TloB[0] = 0.f;
    TloB[4] = 0.f + hr[4];
    TloB[2] = 0.f + hr[5];
    TloB[6] = hr[4] + hr[5];
    TloB[1] = 0.f + hr[6];
    TloB[5] = hr[4] + hr[6];
    TloB[3] = hr[5] + hr[6];
    TloB[7] = (hr[4] + hr[5]) + hr[6];
    const int pq = ((q >> 1) ^ q) & 1;          // popc(q)&1
    const float hpE = pq ? hr[7] : 0.f;         // parity(kk)==0 -> add iff pq
    const float hpO = pq ? 0.f : hr[7];         // parity(kk)==1 -> add iff !pq
    const int hbase = 112 + (q << 5);
#pragma unroll
    for (int kk = 0; kk < 32; ++kk) {
      float tl = TloB[kk & 7] + ((__popc(kk) & 1) ? hpO : hpE);
      float T = Th[kk >> 3] + tl;
      float dot = sumhr - 2.f * T;
      float sq = fmaf(-2.f, dot, ssum) + 2.f;
      if (sq < bestSq) { bestSq = sq; bestIdx = hbase + kk; }
    }
  }
  // cross-lane combine: lexicographic (sq, idx) min == global first-min
  {
#pragma unroll
    for (int mlev = 1; mlev <= 2; mlev <<= 1) {
      float oSq = __shfl_xor(bestSq, mlev, 64);
      int   oIx = __shfl_xor(bestIdx, mlev, 64);
      if (oSq < bestSq || (oSq == bestSq && oIx < bestIdx)) { bestSq = oSq; bestIdx = oIx; }
    }
    if (q == 0 && el < B) outi[el] = (float)bestIdx;
  }

  // ---- coalesced weights store ----
  __syncthreads();
  {
    const size_t wbase = (size_t)blockIdx.x * 448;
    const size_t wtot = (size_t)B * 7;
#pragma unroll
    for (int k2 = 0; k2 < 2; ++k2) {
      int idx2 = k2 * 256 + t;
      if (idx2 < 448 && wbase + idx2 < wtot) outw[wbase + idx2] = wlds[idx2];
    }
  }
#undef LDX
}

extern "C" void kernel_launch(void* const* d_in, const int* in_sizes, int n_in,
                              void* d_out, int out_size, void* d_ws, size_t ws_size,
                              hipStream_t stream) {
  const float* colony = (const float*)d_in[0];
  const float* conf   = (const float*)d_in[1];
  const float* Wq     = (const float*)d_in[2];
  const float* bq     = (const float*)d_in[3];
  const float* Wk     = (const float*)d_in[4];
  const float* bk     = (const float*)d_in[5];
  const float* Wv     = (const float*)d_in[6];
  const float* bv     = (const float*)d_in[7];
  const float* comm   = (const float*)d_in[8];
  const float* role   = (const float*)d_in[9];
  const float* mhaw   = (const float*)d_in[10];
  const float* mhab   = (const float*)d_in[11];
  const float* W1     = (const float*)d_in[12];
  const float* b1     = (const float*)d_in[13];
  const float* W2     = (const float*)d_in[14];
  const float* b2     = (const float*)d_in[15];
  const float* gate   = (const float*)d_in[16];

  int B = in_sizes[0] / 56;
  dim3 grid((B + 63) / 64), block(256);
  hipLaunchKernelGGL(e8_kernel, grid, block, 0, stream,
                     colony, conf, Wq, bq, Wk, bk, Wv, bv, comm, role,
                     mhaw, mhab, W1, b1, W2, b2, gate, (float*)d_out, B);
}

// Round 12
// 144.868 us; speedup vs baseline: 1.1221x; 1.0091x over previous
//
#include <hip/hip_runtime.h>
#include <math.h>

#define INV_SQRT2 0.70710678118654752f
#define INV_SQRT32 0.17677669529663689f
#define KSCALE 1.02013944540889587f   // (1/sqrt(2)) * log2(e), folded into K

// 4 threads per element (quad q = t&3). 256 thr/block -> 64 elements/block.
// Round-11 structure (146us, conflicts 10x down) + instruction cuts:
//  - MHA: K pre-scaled by (invsqrt2*log2e) at staging; softmax without max
//    (logits bounded), exp2f (1 v_exp) + v_rcp instead of IEEE div.
//  - integer-root argmin: c = si*r[i] + sj*r[j] with per-lane exact signs
//    (bit-identical to +-(r[i]+-r[j]) selects; negation+RN are sign-symmetric).
// x_lds [elem][feature] stride 57 (conflict-free); W1 transposed in LDS.
// Order-sensitive sums (xm, mhs, o8) use canonical butterfly; no occupancy
// attributes (rounds 2-6: hints => allocator over-squeeze => scratch spill).
__device__ __forceinline__ void nearest_d8(const float* xx, float* y) {
  float f[8], err[8];
#pragma unroll
  for (int d = 0; d < 8; ++d) { f[d] = rintf(xx[d]); err[d] = xx[d] - f[d]; }
  int idx = 0; float best = -1.0f;
#pragma unroll
  for (int d = 0; d < 8; ++d) { float a = fabsf(err[d]); if (a > best) { best = a; idx = d; } }
  float fs = 0.f;
#pragma unroll
  for (int d = 0; d < 8; ++d) fs += f[d];
  bool ok = ((((int)fs) & 1) == 0);
#pragma unroll
  for (int d = 0; d < 8; ++d) {
    float g = f[d] + ((d == idx) ? ((err[d] >= 0.f) ? 1.f : -1.f) : 0.f);
    y[d] = ok ? f[d] : g;
  }
}

// canonical quad sum ((p0+p1)+(p2+p3)); all 4 lanes end with identical bits
__device__ __forceinline__ float qsum(float v, int q) {
  float o1 = __shfl_xor(v, 1, 64);
  float s1 = (q & 1) ? (o1 + v) : (v + o1);
  float o2 = __shfl_xor(s1, 2, 64);
  return (q & 2) ? (o2 + s1) : (s1 + o2);
}

__device__ __forceinline__ float fast_rcp(float x) {
  float r;
  asm("v_rcp_f32 %0, %1" : "=v"(r) : "v"(x));
  return r;
}

extern "C" __global__ void __launch_bounds__(256)
e8_kernel(const float* __restrict__ colony, const float* __restrict__ conf,
          const float* __restrict__ Wq, const float* __restrict__ bq,
          const float* __restrict__ Wk, const float* __restrict__ bk,
          const float* __restrict__ Wv, const float* __restrict__ bv,
          const float* __restrict__ comm, const float* __restrict__ role,
          const float* __restrict__ mha_w, const float* __restrict__ mha_b,
          const float* __restrict__ W1, const float* __restrict__ b1,
          const float* __restrict__ W2, const float* __restrict__ b2,
          const float* __restrict__ gate, float* __restrict__ out, int B)
{
  __shared__ float x_lds[64 * 57];    // [elem eloc][feature f], stride 57
  __shared__ float wlds[7 * 64];      // block's outw image for coalesced store
  __shared__ float sM8[64], sU[8], sV[8], sCc[1];
  __shared__ float sComm[49], sRole[7];
  __shared__ float sWq3[64], sWk3[64], sBq3[8], sBk3[8];
  __shared__ float sWv[64], sBv[8];
  __shared__ float sW1T[256], sB1[32], sW2[256], sB2[8];
  __shared__ float sGate[1];

  const int t = threadIdx.x;
  if (t < 64) {
    int i = t >> 3, j = t & 7;
    float a = 0.f;
    for (int h = 0; h < 32; ++h) a += Wq[h * 8 + i] * Wk[h * 8 + j];
    sM8[t] = a;
    sWq3[t] = mha_w[t];
    sWk3[t] = mha_w[64 + t] * KSCALE;    // fold invsqrt2*log2e into K
    sWv[t] = Wv[t];
  } else if (t < 72) {
    int j = t - 64;
    float a = 0.f, bb = 0.f;
    for (int h = 0; h < 32; ++h) { a += bq[h] * Wk[h * 8 + j]; bb += bk[h] * Wq[h * 8 + j]; }
    sU[j] = a; sV[j] = bb;
    sBq3[j] = mha_b[j]; sBk3[j] = mha_b[8 + j] * KSCALE;
    sBv[j] = bv[j]; sB2[j] = b2[j];
  } else if (t == 72) {
    float c = 0.f;
    for (int h = 0; h < 32; ++h) c += bq[h] * bk[h];
    sCc[0] = c;
    sGate[0] = 1.f / (1.f + expf(-gate[0]));
  } else if (t >= 80 && t < 87) {
    int n = t - 80;
    float mx = -1e30f;
    for (int m = 0; m < 7; ++m) mx = fmaxf(mx, comm[n * 7 + m]);
    float ee[7], s = 0.f;
    for (int m = 0; m < 7; ++m) { ee[m] = expf(comm[n * 7 + m] - mx); s += ee[m]; }
    for (int m = 0; m < 7; ++m) sComm[n * 7 + m] = ee[m] / s;
  } else if (t == 87) {
    float mx = -1e30f;
    for (int m = 0; m < 7; ++m) mx = fmaxf(mx, role[m]);
    float ee[7], s = 0.f;
    for (int m = 0; m < 7; ++m) { ee[m] = expf(role[m] - mx); s += ee[m]; }
    for (int m = 0; m < 7; ++m) sRole[m] = ee[m] / s;
  }
  sW1T[t] = W1[((t & 31) << 3) + (t >> 5)];   // sW1T[j*32+i] = W1[i*8+j]
  sW2[t] = W2[t];
  if (t < 32) sB1[t] = b1[t];

  const int q    = t & 3;
  const int eloc = t >> 2;
  const int el   = blockIdx.x * 64 + eloc;
  const int ec   = (el < B) ? el : (B - 1);   // clamped loads, no early return
  const bool q3  = (q < 3);
  const int n1 = q;
  const int n2 = q3 ? q + 4 : 3;   // lane3 harmlessly redoes row 3

#define LDX(n, j) x_lds[eloc * 57 + (((n) << 3) + (j))]

  // ---- load + normalize my 2 rows -> LDS ----
  {
    const float* px = colony + (size_t)ec * 56;
#pragma unroll
    for (int rr = 0; rr < 2; ++rr) {
      int n = rr ? n2 : n1;
      float4 v0 = *(const float4*)(px + n * 8);
      float4 v1 = *(const float4*)(px + n * 8 + 4);
      float row[8] = { v0.x, v0.y, v0.z, v0.w, v1.x, v1.y, v1.z, v1.w };
      float ss = 0.f;
#pragma unroll
      for (int d = 0; d < 8; ++d) ss += row[d] * row[d];
      float inv = 1.0f / fmaxf(sqrtf(ss), 1e-12f);
#pragma unroll
      for (int d = 0; d < 8; ++d) x_lds[eloc * 57 + ((n << 3) + d)] = row[d] * inv;
    }
  }
  __syncthreads();

  // ---- xm via canonical quad sum ----
  float xm[8];
#pragma unroll
  for (int d = 0; d < 8; ++d) {
    float a = LDX(n1, d);
    float bpart = LDX(n2, d);
    float p = q3 ? (a + bpart) : a;
    xm[d] = qsum(p, q) * (1.0f / 7.0f);
  }

  // ---- w8 split: lane q owns j=q and j=q+4 (exact sequential dots) ----
  float w8[8];
  {
    float a0 = 0.f, a1 = 0.f;
#pragma unroll
    for (int i = 0; i < 8; ++i) {
      a0 += xm[i] * sM8[i * 8 + q];
      a1 += xm[i] * sM8[i * 8 + q + 4];
    }
    a0 += sU[q]; a1 += sU[q + 4];
#pragma unroll
    for (int j = 0; j < 4; ++j) w8[j] = __shfl(a0, j, 4);
#pragma unroll
    for (int j = 4; j < 8; ++j) w8[j] = __shfl(a1, j - 4, 4);
  }
  float base = sCc[0];
#pragma unroll
  for (int i = 0; i < 8; ++i) base += sV[i] * xm[i];

  // ---- sc split: lane q owns n1, n2 ----
  float sc[7];
  {
    float sA = base, sB_ = base;
#pragma unroll
    for (int j = 0; j < 8; ++j) {
      sA  += w8[j] * LDX(n1, j);
      sB_ += w8[j] * LDX(n2, j);
    }
    sA *= INV_SQRT32; sB_ *= INV_SQRT32;
#pragma unroll
    for (int n = 0; n < 4; ++n) sc[n] = __shfl(sA, n, 4);
#pragma unroll
    for (int n = 4; n < 7; ++n) sc[n] = __shfl(sB_, n - 4, 4);
  }

  // ---- sc2 split: lane q owns m=q and m=n2 ----
  float sc2[7];
  {
    float a0 = 0.f, a1 = 0.f;
#pragma unroll
    for (int n = 0; n < 7; ++n) {
      a0 += sc[n] * sComm[n * 7 + q];
      a1 += sc[n] * sComm[n * 7 + n2];
    }
    a0 += sRole[q]; a1 += sRole[n2];
#pragma unroll
    for (int m = 0; m < 4; ++m) sc2[m] = __shfl(a0, m, 4);
#pragma unroll
    for (int m = 4; m < 7; ++m) sc2[m] = __shfl(a1, m - 4, 4);
  }

  // ---- MHA: 1 head per lane (h = q); K pre-scaled; softmax w/o max ----
  float mhs[7];
  {
    float Kh[7][2], Qh[7][2];
#pragma unroll
    for (int m = 0; m < 7; ++m) {
      float row[8];
#pragma unroll
      for (int j = 0; j < 8; ++j) row[j] = LDX(m, j);
      float k0 = sBk3[2 * q], k1 = sBk3[2 * q + 1];
      float q0 = sBq3[2 * q], q1 = sBq3[2 * q + 1];
#pragma unroll
      for (int j = 0; j < 8; ++j) {
        k0 += row[j] * sWk3[(2 * q) * 8 + j];
        k1 += row[j] * sWk3[(2 * q + 1) * 8 + j];
        q0 += row[j] * sWq3[(2 * q) * 8 + j];
        q1 += row[j] * sWq3[(2 * q + 1) * 8 + j];
      }
      Kh[m][0] = k0; Kh[m][1] = k1;
      Qh[m][0] = q0; Qh[m][1] = q1;
    }
    float mp[7];
#pragma unroll
    for (int m = 0; m < 7; ++m) mp[m] = 0.f;
#pragma unroll
    for (int n = 0; n < 7; ++n) {
      float ex[7], s = 0.f;
#pragma unroll
      for (int m = 0; m < 7; ++m) {
        ex[m] = exp2f(Qh[n][0] * Kh[m][0] + Qh[n][1] * Kh[m][1]);
        s += ex[m];
      }
      float inv = fast_rcp(s);
#pragma unroll
      for (int m = 0; m < 7; ++m) mp[m] += ex[m] * inv;
    }
#pragma unroll
    for (int m = 0; m < 7; ++m) mhs[m] = qsum(mp[m], q);
  }

  // ---- combine scores, softmax, confidence re-norm (redundant, identical) ----
  float scf[7], mx2 = -1e30f;
#pragma unroll
  for (int m = 0; m < 7; ++m) {
    scf[m] = 0.7f * sc2[m] + 0.3f * ((mhs[m] * 0.25f) * (1.0f / 7.0f));
    mx2 = fmaxf(mx2, scf[m]);
  }
  float ew[7], s2 = 0.f;
#pragma unroll
  for (int m = 0; m < 7; ++m) { ew[m] = __expf(scf[m] - mx2); s2 += ew[m]; }
  float sinv = 1.0f / s2;
  float w[7], ws = 0.f;
  const float* pc = conf + (size_t)ec * 7;
#pragma unroll
  for (int m = 0; m < 7; ++m) { w[m] = (ew[m] * sinv) * pc[m]; ws += w[m]; }
  float dinv = 1.0f / fmaxf(ws, 1e-8f);
#pragma unroll
  for (int m = 0; m < 7; ++m) w[m] = w[m] * dinv;

  if (q == 0) {
#pragma unroll
    for (int m = 0; m < 7; ++m) wlds[eloc * 7 + m] = w[m];
  }

  // ---- xc split by dim: lane q owns d=q and d=q+4 (exact n-order chains) ----
  float xc[8];
  {
    float a0 = 0.f, a1 = 0.f;
#pragma unroll
    for (int n = 0; n < 7; ++n) {
      a0 += w[n] * LDX(n, q);
      a1 += w[n] * LDX(n, q + 4);
    }
#pragma unroll
    for (int d = 0; d < 4; ++d) xc[d] = __shfl(a0, d, 4);
#pragma unroll
    for (int d = 4; d < 8; ++d) xc[d] = __shfl(a1, d - 4, 4);
  }

  // ---- comb split: lane q owns i=q and i=q+4 ----
  float comb[8];
  {
    float a0 = sBv[q], a1 = sBv[q + 4];
#pragma unroll
    for (int j = 0; j < 8; ++j) {
      a0 += sWv[q * 8 + j] * xc[j];
      a1 += sWv[(q + 4) * 8 + j] * xc[j];
    }
#pragma unroll
    for (int i = 0; i < 4; ++i) comb[i] = __shfl(a0, i, 4);
#pragma unroll
    for (int i = 4; i < 8; ++i) comb[i] = __shfl(a1, i - 4, 4);
  }

  // ---- MLP: 8 neurons per lane (i = 8q..8q+7), canonical combine ----
  float o8[8];
  {
    float op[8];
#pragma unroll
    for (int k = 0; k < 8; ++k) op[k] = (q == 0) ? sB2[k] : 0.f;
#pragma unroll
    for (int ii = 0; ii < 8; ++ii) {
      int i = 8 * q + ii;
      float a = sB1[i];
#pragma unroll
      for (int j = 0; j < 8; ++j) a += sW1T[j * 32 + i] * comb[j];
      float g = 0.5f * a * (1.f + erff(a * INV_SQRT2));
#pragma unroll
      for (int k = 0; k < 8; ++k) op[k] += sW2[k * 32 + i] * g;
    }
#pragma unroll
    for (int k = 0; k < 8; ++k) o8[k] = qsum(op[k], q);
  }

  // ---- refined = norm(combined + sigmoid(gate)*h) (redundant, identical) ----
  float gsig = sGate[0];
  float pre[8], ssq = 0.f;
#pragma unroll
  for (int d = 0; d < 8; ++d) { pre[d] = comb[d] + gsig * o8[d]; ssq += pre[d] * pre[d]; }
  float ninv = 1.0f / fmaxf(sqrtf(ssq), 1e-12f);
  float r[8];
#pragma unroll
  for (int d = 0; d < 8; ++d) r[d] = pre[d] * ninv;

  float* outq = out;
  float* outi = out + (size_t)B * 8;
  float* outw = out + (size_t)B * 9;

  // ---- nearest E8: lanes q<2 compute y0, q>=2 compute y1 ----
  {
    const int h2 = q >> 1;
    float xs[8], y[8];
#pragma unroll
    for (int d = 0; d < 8; ++d) xs[d] = h2 ? (r[d] - 0.5f) : r[d];
    nearest_d8(xs, y);
#pragma unroll
    for (int d = 0; d < 8; ++d) y[d] = h2 ? (y[d] + 0.5f) : y[d];
    float dow = 0.f;
#pragma unroll
    for (int d = 0; d < 8; ++d) { float dd = r[d] - y[d]; dow += dd * dd; }
    float doth = __shfl_xor(dow, 2, 64);
    float dd0 = h2 ? doth : dow;
    float dd1 = h2 ? dow : doth;
    bool use0 = (dd0 <= dd1);
    bool mine_wins = (use0 == (h2 == 0));
    if (mine_wins && ((q & 1) == 0) && el < B) {
      float qv[8];
#pragma unroll
      for (int d = 0; d < 8; ++d) qv[d] = r[d] + (y[d] - r[d]);
      *(float4*)(outq + (size_t)el * 8)     = make_float4(qv[0], qv[1], qv[2], qv[3]);
      *(float4*)(outq + (size_t)el * 8 + 4) = make_float4(qv[4], qv[5], qv[6], qv[7]);
    }
  }

  // ---- argmin over 240 E8 roots, quartered ----
  float ssum = 0.f;
#pragma unroll
  for (int d = 0; d < 8; ++d) ssum += r[d] * r[d];
  float bestSq = 1e30f;
  int bestIdx = 0;
  // integer roots: lane q takes sign-combo s4=q; c = si*r[i] + sj*r[j] with
  // si=(q&2)?-1:+1, sj=(q&1)?-1:+1 -- bit-identical to +-(r[i]+-r[j]) since
  // negation is exact and round-to-nearest is sign-symmetric.
  {
    const float si = (q & 2) ? -1.f : 1.f;
    const float sj = (q & 1) ? -1.f : 1.f;
    float sri[8], srj[8];
#pragma unroll
    for (int d = 0; d < 8; ++d) { sri[d] = si * r[d]; srj[d] = sj * r[d]; }
    int idx = 0;
#pragma unroll
    for (int i = 0; i < 8; ++i) {
#pragma unroll
      for (int j = i + 1; j < 8; ++j) {
        float c = sri[i] + srj[j];
        float sq = fmaf(-2.f, c, ssum) + 2.f;
        if (sq < bestSq) { bestSq = sq; bestIdx = idx; }
        idx += 4;
      }
    }
    bestIdx += q;   // absolute index (a hit always occurred)
  }
  // half-integer roots: lane q takes k = 32q..32q+31 (tables built in the
  // exact add order of the passing full-table chain).
  {
    float hr[8];
#pragma unroll
    for (int d = 0; d < 8; ++d) hr[d] = 0.5f * r[d];
    float sumhr = ((hr[0] + hr[1]) + (hr[2] + hr[3])) + ((hr[4] + hr[5]) + (hr[6] + hr[7]));
    float tb0 = (q & 2) ? hr[0] : 0.f;
    float tb  = (q & 1) ? (tb0 + hr[1]) : tb0;
    float Th[4];
    Th[0] = tb;
    Th[1] = tb + hr[3];
    Th[2] = tb + hr[2];
    Th[3] = (tb + hr[2]) + hr[3];
    float TloB[8];
    TloB[0] = 0.f;
    TloB[4] = 0.f + hr[4];
    TloB[2] = 0.f + hr[5];
    TloB[6] = hr[4] + hr[5];
    TloB[1] = 0.f + hr[6];
    TloB[5] = hr[4] + hr[6];
    TloB[3] = hr[5] + hr[6];
    TloB[7] = (hr[4] + hr[5]) + hr[6];
    const int pq = ((q >> 1) ^ q) & 1;          // popc(q)&1
    const float hpE = pq ? hr[7] : 0.f;         // parity(kk)==0 -> add iff pq
    const float hpO = pq ? 0.f : hr[7];         // parity(kk)==1 -> add iff !pq
    const int hbase = 112 + (q << 5);
#pragma unroll
    for (int kk = 0; kk < 32; ++kk) {
      float tl = TloB[kk & 7] + ((__popc(kk) & 1) ? hpO : hpE);
      float T = Th[kk >> 3] + tl;
      float dot = sumhr - 2.f * T;
      float sq = fmaf(-2.f, dot, ssum) + 2.f;
      if (sq < bestSq) { bestSq = sq; bestIdx = hbase + kk; }
    }
  }
  // cross-lane combine: lexicographic (sq, idx) min == global first-min
  {
#pragma unroll
    for (int mlev = 1; mlev <= 2; mlev <<= 1) {
      float oSq = __shfl_xor(bestSq, mlev, 64);
      int   oIx = __shfl_xor(bestIdx, mlev, 64);
      if (oSq < bestSq || (oSq == bestSq && oIx < bestIdx)) { bestSq = oSq; bestIdx = oIx; }
    }
    if (q == 0 && el < B) outi[el] = (float)bestIdx;
  }

  // ---- coalesced weights store ----
  __syncthreads();
  {
    const size_t wbase = (size_t)blockIdx.x * 448;
    const size_t wtot = (size_t)B * 7;
#pragma unroll
    for (int k2 = 0; k2 < 2; ++k2) {
      int idx2 = k2 * 256 + t;
      if (idx2 < 448 && wbase + idx2 < wtot) outw[wbase + idx2] = wlds[idx2];
    }
  }
#undef LDX
}

extern "C" void kernel_launch(void* const* d_in, const int* in_sizes, int n_in,
                              void* d_out, int out_size, void* d_ws, size_t ws_size,
                              hipStream_t stream) {
  const float* colony = (const float*)d_in[0];
  const float* conf   = (const float*)d_in[1];
  const float* Wq     = (const float*)d_in[2];
  const float* bq     = (const float*)d_in[3];
  const float* Wk     = (const float*)d_in[4];
  const float* bk     = (const float*)d_in[5];
  const float* Wv     = (const float*)d_in[6];
  const float* bv     = (const float*)d_in[7];
  const float* comm   = (const float*)d_in[8];
  const float* role   = (const float*)d_in[9];
  const float* mhaw   = (const float*)d_in[10];
  const float* mhab   = (const float*)d_in[11];
  const float* W1     = (const float*)d_in[12];
  const float* b1     = (const float*)d_in[13];
  const float* W2     = (const float*)d_in[14];
  const float* b2     = (const float*)d_in[15];
  const float* gate   = (const float*)d_in[16];

  int B = in_sizes[0] / 56;
  dim3 grid((B + 63) / 64), block(256);
  hipLaunchKernelGGL(e8_kernel, grid, block, 0, stream,
                     colony, conf, Wq, bq, Wk, bk, Wv, bv, comm, role,
                     mhaw, mhab, W1, b1, W2, b2, gate, (float*)d_out, B);
}